// Round 1
// baseline (48.576 us; speedup 1.0000x reference)
//
#include <hip/hip_runtime.h>

namespace {
constexpr int Bc  = 16;
constexpr int Nc  = 96;
constexpr int KRc = 16;
constexpr int KAc = 8;
constexpr int NNb   = Nc - 1;                 // 95 neighbors per atom
constexpr int NPAIR = NNb * (NNb - 1) / 2;    // 4465 unordered pairs
constexpr float RCRf  = 5.2f;
constexpr float RCAf  = 3.5f;
constexpr float LOG2E = 1.4426950408889634f;
constexpr float PIf   = 3.14159265358979323846f;
}

__global__ __launch_bounds__(256) void ani_feat_kernel(
    const float* __restrict__ coords,      // (B,N,3)
    const int*   __restrict__ atom_types,  // (N,)
    const float* __restrict__ EtaR,        // (T,KR)
    const float* __restrict__ ShfR,        // (T,KR)
    const float* __restrict__ Zeta,        // (T,KA)
    const float* __restrict__ EtaA,        // (T,KA)
    float* __restrict__ out)               // (B,N,KR+KA)
{
    const int bi = blockIdx.x;             // b*N + i
    const int b  = bi / Nc;
    const int i  = bi - b * Nc;
    const int t  = threadIdx.x;

    __shared__ float cx[Nc], cy[Nc], cz[Nc];
    __shared__ float sx[NNb], sy[NNb], sz[NNb];
    __shared__ float sd[NNb], sd2[NNb], sfr[NNb], sfa[NNb];
    __shared__ float g2s[KRc];
    __shared__ float red[4][KAc];

    // stage this batch's coordinates
    for (int j = t; j < Nc; j += 256) {
        cx[j] = coords[(b * Nc + j) * 3 + 0];
        cy[j] = coords[(b * Nc + j) * 3 + 1];
        cz[j] = coords[(b * Nc + j) * 3 + 2];
    }
    if (t < KRc) g2s[t] = 0.0f;
    __syncthreads();

    // per-neighbor precompute: rij = coords[i] - coords[j], j != i ascending
    const float xi = cx[i], yi = cy[i], zi = cz[i];
    for (int jj = t; jj < NNb; jj += 256) {
        int j = jj + (jj >= i);
        float dx = xi - cx[j], dy = yi - cy[j], dz = zi - cz[j];
        float d2 = dx * dx + dy * dy + dz * dz;
        float d  = sqrtf(d2);
        sx[jj] = dx; sy[jj] = dy; sz[jj] = dz;
        sd[jj] = d;  sd2[jj] = d2;
        sfr[jj] = 0.5f * (cosf(d * (PIf / RCRf)) + 1.0f);   // radial cutoff (RCR)
        sfa[jj] = 0.5f * (cosf(d * (PIf / RCAf)) + 1.0f);   // angular cutoff (RCA)
    }
    __syncthreads();

    const int ti = atom_types[i];

    // ---- radial G2: sum_j exp(-er*(d-sr)^2) * f(d; RCR) ----
    for (int w = t; w < NNb * KRc; w += 256) {
        int k  = w & (KRc - 1);
        int jj = w >> 4;
        float er = EtaR[ti * KRc + k];
        float sr = ShfR[ti * KRc + k];
        float dd = sd[jj] - sr;
        float term = expf(-er * dd * dd) * sfr[jj];
        atomicAdd(&g2s[k], term);
    }

    // ---- angular G3 over unordered neighbor pairs ----
    float zek[KAc], c1k[KAc], eaL[KAc];
#pragma unroll
    for (int k = 0; k < KAc; ++k) {
        float z = Zeta[ti * KAc + k];
        zek[k] = z;
        c1k[k] = 1.0f - z;                       // exponent base-2 constant
        eaL[k] = EtaA[ti * KAc + k] * LOG2E;     // eta scaled to base-2
    }
    float acc[KAc];
#pragma unroll
    for (int k = 0; k < KAc; ++k) acc[k] = 0.0f;

    for (int p = t; p < NPAIR; p += 256) {
        // decode triangular index: S(j1) = j1*(189-j1)/2, NN=95
        float disc = 35721.0f - 8.0f * (float)p;      // 189^2 - 8p
        int j1 = (int)((189.0f - sqrtf(disc)) * 0.5f);
        int base = (j1 * (189 - j1)) >> 1;
        if (base > p) { --j1; base = (j1 * (189 - j1)) >> 1; }
        else {
            int nb = ((j1 + 1) * (188 - j1)) >> 1;
            if (p >= nb) { ++j1; base = nb; }
        }
        int j2 = p - base + j1 + 1;

        float ax = sx[j1], ay = sy[j1], az = sz[j1];
        float bx = sx[j2], by = sy[j2], bz = sz[j2];
        float dotv = ax * bx + ay * by + az * bz;
        float d12 = sd[j1], d13 = sd[j2];
        float rx = ax - bx, ry = ay - by, rz = az - bz;
        float d23sq = rx * rx + ry * ry + rz * rz;
        float d23 = sqrtf(d23sq);
        float f23 = 0.5f * (cosf(d23 * (PIf / RCAf)) + 1.0f);
        float fprod = sfa[j1] * sfa[j2] * f23;

        float cosv = dotv / (d12 * d13);
        float tt = fmaxf(1.0f + cosv, 0.0f);          // guard pow(neg,32) -> 0
        float l2 = log2f(tt);                          // -inf at tt==0 is fine
        float s = sd2[j1] + sd2[j2] + d23sq;

#pragma unroll
        for (int k = 0; k < KAc; ++k) {
            float E = c1k[k] + zek[k] * l2 - eaL[k] * s;
            acc[k] += exp2f(E) * fprod;
        }
    }

    // block reduction of angular accumulators
    const int lane = t & 63, wave = t >> 6;
#pragma unroll
    for (int k = 0; k < KAc; ++k) {
        float v = acc[k];
        for (int off = 32; off > 0; off >>= 1) v += __shfl_down(v, off, 64);
        if (lane == 0) red[wave][k] = v;
    }
    __syncthreads();

    if (t < KAc) {
        float v = red[0][t] + red[1][t] + red[2][t] + red[3][t];
        out[bi * (KRc + KAc) + KRc + t] = v;
    }
    if (t < KRc) {
        out[bi * (KRc + KAc) + t] = g2s[t];
    }
}

extern "C" void kernel_launch(void* const* d_in, const int* in_sizes, int n_in,
                              void* d_out, int out_size, void* d_ws, size_t ws_size,
                              hipStream_t stream) {
    const float* coords     = (const float*)d_in[0];
    const int*   atom_types = (const int*)d_in[1];
    const float* EtaR       = (const float*)d_in[2];
    const float* ShfR       = (const float*)d_in[3];
    const float* Zeta       = (const float*)d_in[4];
    const float* EtaA       = (const float*)d_in[5];
    float* out = (float*)d_out;

    dim3 grid(Bc * Nc);
    dim3 block(256);
    ani_feat_kernel<<<grid, block, 0, stream>>>(coords, atom_types, EtaR, ShfR,
                                                Zeta, EtaA, out);
}

// Round 2
// 21.166 us; speedup vs baseline: 2.2951x; 2.2951x over previous
//
#include <hip/hip_runtime.h>

namespace {
constexpr int Bc  = 16;
constexpr int Nc  = 96;
constexpr int KRc = 16;
constexpr int KAc = 8;
constexpr int NNb   = Nc - 1;              // 95 neighbors per atom
constexpr int NRr   = (NNb - 1) / 2;       // 47 round-robin rounds
constexpr int NPAIR = NRr * NNb;           // 4465 unordered pairs (exact cover)
constexpr float RCRf  = 5.2f;
constexpr float RCAf  = 3.5f;
constexpr float L2E   = 1.4426950408889634f;
}

// cos(2*pi*rev) via HW trans ops; rev >= 0 here
__device__ __forceinline__ float cos_rev(float rev) {
    return __builtin_amdgcn_cosf(__builtin_amdgcn_fractf(rev));
}

__global__ __launch_bounds__(256) void ani_feat_kernel(
    const float* __restrict__ coords,      // (B,N,3)
    const int*   __restrict__ atom_types,  // (N,)
    const float* __restrict__ EtaR,        // (T,KR)
    const float* __restrict__ ShfR,        // (T,KR)
    const float* __restrict__ Zeta,        // (T,KA)
    const float* __restrict__ EtaA,        // (T,KA)
    float* __restrict__ out)               // (B,N,KR+KA)
{
    const int bi = blockIdx.x;             // b*N + i
    const int b  = bi / Nc;
    const int i  = bi - b * Nc;
    const int t  = threadIdx.x;

    __shared__ float4 un[NNb];             // unit vec (x,y,z) + distance d
    __shared__ float  sfa[NNb];            // angular cutoff f(d; RCA)
    __shared__ float  sdr[NNb];            // d (radial use)
    __shared__ float  sfr[NNb];            // radial cutoff f(d; RCR)
    __shared__ float  pr[16][KRc];         // radial partials
    __shared__ float  red[4][KAc];         // angular wave partials

    const int ti = atom_types[i];

    // ---- stage per-neighbor data (one thread per neighbor) ----
    if (t < NNb) {
        const float* cb = coords + (size_t)(b * Nc) * 3;
        int j = t + (t >= i);
        float xi = cb[i*3+0], yi = cb[i*3+1], zi = cb[i*3+2];
        float dx = xi - cb[j*3+0];
        float dy = yi - cb[j*3+1];
        float dz = zi - cb[j*3+2];
        float d2 = dx*dx + dy*dy + dz*dz;
        float d  = __builtin_amdgcn_sqrtf(d2);
        float inv = 1.0f / d;
        un[t]  = make_float4(dx*inv, dy*inv, dz*inv, d);
        sdr[t] = d;
        sfa[t] = fmaf(cos_rev(d * (0.5f / RCAf)), 0.5f, 0.5f);
        sfr[t] = fmaf(cos_rev(d * (0.5f / RCRf)), 0.5f, 0.5f);
    }

    // ---- angular parameters + scalar-uniform fast-path detection ----
    float zek[KAc], c1k[KAc], eaL[KAc];
#pragma unroll
    for (int k = 0; k < KAc; ++k) {
        float z = Zeta[ti * KAc + k];
        zek[k] = z;
        c1k[k] = 1.0f - z;
        eaL[k] = EtaA[ti * KAc + k] * L2E;
    }
    bool zuni = true;
#pragma unroll
    for (int k = 1; k < KAc; ++k) zuni = zuni && (zek[k] == zek[0]);
    const float dL = eaL[1] - eaL[0];
    bool arith = true;
#pragma unroll
    for (int k = 2; k < KAc; ++k)
        arith = arith && (fabsf(eaL[k] - (eaL[0] + dL * (float)k)) <=
                          1e-5f * fabsf(eaL[k]) + 1e-7f);
    const bool fast = zuni && arith;
    const bool z32  = (zek[0] == 32.0f);
    const float z0 = zek[0], c10 = c1k[0], ea0 = eaL[0];
    const float p21z = __builtin_amdgcn_exp2f(c10);   // 2^(1-z)

    __syncthreads();

    // ---- radial G2: k per lane-of-16, register accumulate, no atomics ----
    {
        const int k = t & 15, g = t >> 4;
        float er  = EtaR[ti * KRc + k];
        float sr  = ShfR[ti * KRc + k];
        float erL = -er * L2E;
        float acc = 0.0f;
        for (int jj = g; jj < NNb; jj += 16) {
            float dd = sdr[jj] - sr;
            acc += __builtin_amdgcn_exp2f(erL * dd * dd) * sfr[jj];
        }
        pr[g][k] = acc;
    }

    // ---- angular G3: round-robin dense pair enumeration ----
    float acc[KAc];
#pragma unroll
    for (int k = 0; k < KAc; ++k) acc[k] = 0.0f;

#pragma unroll 2
    for (int idx = t; idx < NPAIR; idx += 256) {
        int rr = idx / NNb;                 // 0..46  (round - 1)
        int j  = idx - rr * NNb;            // 0..94
        int j2 = j + rr + 1; if (j2 >= NNb) j2 -= NNb;

        float4 A  = un[j];
        float4 Bv = un[j2];
        float faf = sfa[j] * sfa[j2];

        float cosv = fmaf(A.x, Bv.x, fmaf(A.y, Bv.y, A.z * Bv.z));
        float d2A = A.w * A.w, d2B = Bv.w * Bv.w;
        float sAB = d2A + d2B;
        float d23sq = fmaxf(fmaf(-2.0f * A.w * Bv.w, cosv, sAB), 0.0f);
        float d23 = __builtin_amdgcn_sqrtf(d23sq);
        float f23 = fmaf(cos_rev(d23 * (0.5f / RCAf)), 0.5f, 0.5f);
        float fprod = faf * f23;
        float s  = sAB + d23sq;
        float tt = fmaxf(1.0f + cosv, 0.0f);

        if (fast) {
            float P;
            if (z32) {
                float t2 = tt*tt, t4 = t2*t2, t8 = t4*t4, t16 = t8*t8;
                P = t16 * t16 * p21z;                      // tt^32 * 2^(1-32)
            } else {
                P = __builtin_amdgcn_exp2f(
                        fmaf(z0, __builtin_amdgcn_logf(tt), c10));
            }
            float F = P * fprod;
            float e = __builtin_amdgcn_exp2f(-ea0 * s);
            float q = __builtin_amdgcn_exp2f(-dL * s);
#pragma unroll
            for (int k = 0; k < KAc; ++k) {
                acc[k] = fmaf(F, e, acc[k]);
                e *= q;
            }
        } else {
            float l2 = __builtin_amdgcn_logf(tt);          // -inf at 0 is fine
#pragma unroll
            for (int k = 0; k < KAc; ++k) {
                float E = fmaf(zek[k], l2, c1k[k]);
                E = fmaf(-eaL[k], s, E);
                acc[k] += __builtin_amdgcn_exp2f(E) * fprod;
            }
        }
    }

    // ---- reductions ----
    const int lane = t & 63, wave = t >> 6;
#pragma unroll
    for (int k = 0; k < KAc; ++k) {
        float v = acc[k];
#pragma unroll
        for (int off = 32; off; off >>= 1) v += __shfl_xor(v, off, 64);
        if (lane == 0) red[wave][k] = v;
    }
    __syncthreads();

    if (t < KAc) {
        out[bi * (KRc + KAc) + KRc + t] =
            red[0][t] + red[1][t] + red[2][t] + red[3][t];
    }
    if (t < KRc) {
        float s = 0.0f;
#pragma unroll
        for (int g = 0; g < 16; ++g) s += pr[g][t];
        out[bi * (KRc + KAc) + t] = s;
    }
}

extern "C" void kernel_launch(void* const* d_in, const int* in_sizes, int n_in,
                              void* d_out, int out_size, void* d_ws, size_t ws_size,
                              hipStream_t stream) {
    const float* coords     = (const float*)d_in[0];
    const int*   atom_types = (const int*)d_in[1];
    const float* EtaR       = (const float*)d_in[2];
    const float* ShfR       = (const float*)d_in[3];
    const float* Zeta       = (const float*)d_in[4];
    const float* EtaA       = (const float*)d_in[5];
    float* out = (float*)d_out;

    dim3 grid(Bc * Nc);
    dim3 block(256);
    ani_feat_kernel<<<grid, block, 0, stream>>>(coords, atom_types, EtaR, ShfR,
                                                Zeta, EtaA, out);
}